// Round 16
// baseline (96.253 us; speedup 1.0000x reference)
//
#include <hip/hip_runtime.h>

#define RES   1024
#define NPTS  200000
#define NB    32
#define PPT   8
#define BLK   512
#define NBLK  49          // blocks per batch = ceil(200000/4096)
#define BPB   4096        // points per block
#define NBAND 512         // 512 bands of 2 rows
#define BANDH 2
#define BORD  4096        // 4*1024 border pixels

// ws layout:
//  arena : NB*NBLK*BPB u64   = 51,380,224 B
//  tmeta : NB*NBAND*NBLK u32 =  3,211,264 B   (lofs<<16 | cnt, band-major)
//  bwin  : NB*BORD i32       =    524,288 B
#define OFF_AR 0
#define OFF_TM 51380224
#define OFF_BW 54591488

#define RB_INVALID 0xFFFFFFFFu
#define RB_BORDER  0xFFFFFFFEu

// ---------------------------------------------------------------------------
// Pass 0: init border-winner buffer to -1.
// ---------------------------------------------------------------------------
__global__ __launch_bounds__(256) void k_init(int4* __restrict__ bwin4)
{
    int i = blockIdx.x * 256 + threadIdx.x;          // 32768 int4
    bwin4[i] = make_int4(-1, -1, -1, -1);
}

// ---------------------------------------------------------------------------
// Pass 1 (r15 structure, 512 bands): block's 48 KB pc slab staged into LDS
// with float4 loads, consumed from LDS. Slab aliases sb(16K)+stage(32K).
// Interior -> u64 entries pix(11b)<<53 | n(18b)<<32 | zbits, staged dense in
// LDS, dumped coalesced. Border -> sb[4096] pre-reduction -> bwin atomicMax.
// Dot products replicate numpy einsum k=4: separately-rounded products,
// pairwise association, fp contract OFF (bit-exact winner selection).
// ---------------------------------------------------------------------------
__global__ __launch_bounds__(BLK) void k_bin(
        const float* __restrict__ pc,   // (B,N,3)
        const float* __restrict__ tm,   // (B,3,4)
        unsigned long long* __restrict__ arena,
        unsigned int* __restrict__ tmeta,
        int* __restrict__ bwin)         // (B,4096) init -1
{
#pragma clang fp contract(off)
    const int b   = blockIdx.y;
    const int tid = threadIdx.x;
    const int gg  = b * NBLK + blockIdx.x;

    __shared__ __align__(16) char smem[49152];        // 48 KB, phase-aliased
    __shared__ unsigned int hist[NBAND];
    __shared__ unsigned int lofs[NBAND];

    float*              pcs   = (float*)smem;                     // ph 1-2
    float4*             pcs4  = (float4*)smem;
    int*                sb    = (int*)smem;                       // ph 3+
    unsigned long long* stage = (unsigned long long*)(smem + 16384);

    const int blk0     = blockIdx.x * BPB;
    const int npts_blk = min(BPB, NPTS - blk0);       // 4096 (3392 last)
    const float* pcb   = pc + (size_t)b * NPTS * 3;

    // ---- phase 1: cooperative float4 staging of this block's pc slab
    const int nf4 = (npts_blk * 3) >> 2;              // 3072 / 2544, exact
    const float4* src4 = (const float4*)pcb + ((size_t)blk0 * 3 >> 2);
    for (int i = tid; i < nf4; i += BLK) pcs4[i] = src4[i];
    hist[tid] = 0u;                                   // BLK == NBAND == 512
    __syncthreads();

    // ---- phase 2: per-point transform + binning (reads from LDS)
    const float* M = tm + b * 12;
    const float m0 = M[0], m1 = M[1], m2  = M[2],  m3  = M[3];
    const float m4 = M[4], m5 = M[5], m6  = M[6],  m7  = M[7];
    const float m8 = M[8], m9 = M[9], m10 = M[10], m11 = M[11];

    unsigned long long ent[PPT];
    unsigned int rb[PPT];

    #pragma unroll
    for (int k = 0; k < PPT; ++k) {
        rb[k] = RB_INVALID;
        int j = k * BLK + tid;
        if (j < npts_blk) {
            float x = pcs[j * 3], y = pcs[j * 3 + 1], z = pcs[j * 3 + 2];
            float tx = (x * m0 + y * m1) + (z * m2  + m3);
            float ty = (x * m4 + y * m5) + (z * m6  + m7);
            float tz = (x * m8 + y * m9) + (z * m10 + m11);
            float nx = tx * 0.5f;
            float ny = ty * 0.5f;
            float nz = tz * 0.5f;
            float px = (nx + 1.0f) * 512.0f;
            float py = (1.0f - ny) * 512.0f;
            px = fminf(fmaxf(px, 0.0f), 1023.0f);
            py = fminf(fmaxf(py, 0.0f), 1023.0f);
            int xi = (int)floorf(px);
            int yi = (int)floorf(py);
            int n  = blk0 + j;

            bool border = (xi == 0) | (xi == 1023) | (yi == 0) | (yi == 1023);
            if (border) {
                int idx = (yi == 0)    ? xi
                        : (yi == 1023) ? 1024 + xi
                        : (xi == 0)    ? 2048 + yi
                                       : 3072 + yi;
                rb[k]  = RB_BORDER;
                ent[k] = ((unsigned long long)(unsigned)idx << 32) | (unsigned)n;
            } else {
                int bin = yi >> 1;                       // 2-row bands
                unsigned r = atomicAdd(&hist[bin], 1u);  // local rank
                rb[k] = ((unsigned)bin << 12) | r;       // r <= 4095, bin <= 511
                unsigned pix = (unsigned)((yi & 1) * RES + xi);   // 11 bits
                ent[k] = ((unsigned long long)pix << 53)
                       | ((unsigned long long)(unsigned)n << 32)
                       | (unsigned long long)__float_as_uint(nz);
            }
        }
    }
    __syncthreads();   // pcs fully consumed; smem can be repurposed

    // ---- phase 3: sb init (aliases pcs!) + hist scan (8 chunks of 64)
    for (int k2 = tid; k2 < BORD; k2 += BLK) sb[k2] = -1;
    if (tid < 64) {
        unsigned carry = 0;
        #pragma unroll
        for (int c = 0; c < 8; ++c) {
            unsigned v = hist[c * 64 + tid];
            unsigned s = v;
            #pragma unroll
            for (int d = 1; d < 64; d <<= 1) {
                unsigned o = __shfl_up(s, d);
                if (tid >= d) s += o;
            }
            lofs[c * 64 + tid] = (s - v) + carry;
            carry += __shfl(s, 63);
        }
    }
    __syncthreads();

    // ---- phase 4: border -> sb atomics; interior -> stage; tmeta
    #pragma unroll
    for (int k = 0; k < PPT; ++k) {
        if (rb[k] == RB_BORDER) {
            atomicMax(&sb[(int)(ent[k] >> 32)], (int)(unsigned)ent[k]);
        } else if (rb[k] != RB_INVALID) {
            unsigned bin = rb[k] >> 12, r = rb[k] & 4095u;
            stage[lofs[bin] + r] = ent[k];
        }
    }
    tmeta[((size_t)(b * NBAND + tid)) * NBLK + blockIdx.x]
        = (lofs[tid] << 16) | hist[tid];              // band = tid (512==512)
    __syncthreads();

    // ---- phase 5: coalesced dump + border flush
    const unsigned Ttot = lofs[NBAND - 1] + hist[NBAND - 1];
    for (unsigned k2 = tid; k2 < Ttot; k2 += BLK)
        arena[(size_t)gg * BPB + k2] = stage[k2];

    for (int k2 = tid; k2 < BORD; k2 += BLK) {
        int v = sb[k2];
        if (v >= 0) atomicMax(&bwin[b * BORD + k2], v);
    }
}

// ---------------------------------------------------------------------------
// Pass 2: one block per (batch, 2-row band) — 16384 buckets, 512 threads,
// 16 KB u64 tile. Hoisted tmeta load; wave-0 prefix scan of 49 segment
// counts; flat cooperative accumulate (idx->seg via 6-step LDS binary
// search); atomicMax key = n<<32|zbits; winner z = low word. Border pixels
// resolve from bwin. Non-temporal u64-packed output stores.
// ---------------------------------------------------------------------------
__global__ __launch_bounds__(512) void k_tile(
        const unsigned long long* __restrict__ arena,
        const unsigned int* __restrict__ tmeta,
        const int* __restrict__ bwin,
        const float* __restrict__ pc,
        const float* __restrict__ tm,
        float* __restrict__ out)
{
#pragma clang fp contract(off)
    const int bucket = blockIdx.x;            // 0 .. NB*NBAND-1
    const int b = bucket >> 9, band = bucket & 511;
    const int tid = threadIdx.x;

    __shared__ __align__(16) unsigned long long tile[BANDH * RES];  // 16384 B
    __shared__ unsigned int pref[NBLK + 1];
    __shared__ unsigned int sbase[NBLK];

    // hoisted meta load (overlaps with tile init below)
    unsigned mv = 0;
    if (tid < NBLK)
        mv = tmeta[((size_t)(b * NBAND + band)) * NBLK + tid];

    for (int k = tid; k < BANDH * RES; k += 512) tile[k] = 0ull;

    if (tid < 64) {
        unsigned cnt = (tid < NBLK) ? (mv & 0xFFFFu) : 0u;
        unsigned s = cnt;
        #pragma unroll
        for (int d = 1; d < 64; d <<= 1) {
            unsigned o = __shfl_up(s, d);
            if (tid >= d) s += o;
        }
        if (tid < NBLK) {
            pref[tid + 1] = s;
            sbase[tid] = (unsigned)((b * NBLK + tid) * BPB) + (mv >> 16);
        }
        if (tid == 0) pref[0] = 0u;
    }
    __syncthreads();

    const unsigned T = pref[NBLK];
    for (unsigned idx = tid; idx < T; idx += 512) {
        int lo = 0, hi = NBLK - 1;
        #pragma unroll
        for (int it = 0; it < 6; ++it) {                // ceil(log2(49)) = 6
            int mid = (lo + hi + 1) >> 1;
            if (pref[mid] <= idx) lo = mid; else hi = mid - 1;
        }
        unsigned long long e = arena[(size_t)sbase[lo] + (idx - pref[lo])];
        atomicMax(&tile[e >> 53], e & 0x001FFFFFFFFFFFFFull);
    }
    __syncthreads();

    const float* M2 = tm + b * 12 + 8;
    const float m8 = M2[0], m9 = M2[1], m10 = M2[2], m11 = M2[3];
    const int y0 = band * BANDH;
    const int* bw = bwin + b * BORD;

    #pragma unroll
    for (int r = 0; r < BANDH; ++r) {
        int yi = y0 + r;
        ulonglong2 kk = ((const ulonglong2*)(tile + r * RES))[tid];
        unsigned zx = (unsigned)(kk.x & 0xFFFFFFFFull);
        unsigned zy = (unsigned)(kk.y & 0xFFFFFFFFull);

        #pragma unroll
        for (int h = 0; h < 2; ++h) {
            int xi = tid * 2 + h;
            bool isb = (yi == 0) | (yi == 1023) | (xi == 0) | (xi == 1023);
            if (isb) {
                int n = (yi == 0)    ? bw[xi]
                      : (yi == 1023) ? bw[1024 + xi]
                      : (xi == 0)    ? bw[2048 + yi]
                                     : bw[3072 + yi];
                float zv = 0.0f;
                if (n >= 0) {
                    const float* p = pc + ((size_t)b * NPTS + n) * 3;
                    float t = (p[0] * m8 + p[1] * m9) + (p[2] * m10 + m11);
                    zv = t * 0.5f;
                }
                if (h) zy = __float_as_uint(zv); else zx = __float_as_uint(zv);
            }
        }
        unsigned long long pv = ((unsigned long long)zy << 32) | zx;
        __builtin_nontemporal_store(pv,
            (unsigned long long*)(out + ((size_t)b * RES + yi) * RES) + tid);
    }
}

// ---------------------------------------------------------------------------
extern "C" void kernel_launch(void* const* d_in, const int* in_sizes, int n_in,
                              void* d_out, int out_size, void* d_ws, size_t ws_size,
                              hipStream_t stream)
{
    const float* pc = (const float*)d_in[0];   // (32,200000,3) f32
    const float* tm = (const float*)d_in[1];   // (32,3,4) f32
    float* out = (float*)d_out;                // (32,1024,1024) f32

    char* ws = (char*)d_ws;
    unsigned long long* arena = (unsigned long long*)(ws + OFF_AR);
    unsigned int* tmeta = (unsigned int*)(ws + OFF_TM);
    int*          bwin  = (int*)         (ws + OFF_BW);

    k_init<<<(NB * BORD / 4) / 256, 256, 0, stream>>>((int4*)bwin);

    dim3 g1(NBLK, NB);
    k_bin<<<g1, BLK, 0, stream>>>(pc, tm, arena, tmeta, bwin);

    k_tile<<<NB * NBAND, 512, 0, stream>>>(arena, tmeta, bwin, pc, tm, out);
}

// Round 17
// 83.070 us; speedup vs baseline: 1.1587x; 1.1587x over previous
//
#include <hip/hip_runtime.h>

#define RES   1024
#define NPTS  200000
#define NB    32
#define PPT   8
#define BLK   512
#define NBLK  49          // blocks per batch = ceil(200000/4096)
#define BPB   4096        // points per block
#define NBAND 256         // 256 bands of 4 rows
#define BANDH 4
#define BORD  4096        // 4*1024 border pixels

// ws layout:
//  arena : NB*NBLK*BPB u64   = 51,380,224 B
//  tmeta : NB*NBAND*NBLK u32 =  1,605,632 B   (lofs<<16 | cnt, band-major)
//  bwin  : NB*BORD i32       =    524,288 B
#define OFF_AR 0
#define OFF_TM 51380224
#define OFF_BW 52985856

#define RB_INVALID 0xFFFFFFFFu
#define RB_BORDER  0xFFFFFFFEu

// ---------------------------------------------------------------------------
// Pass 0: init border-winner buffer to -1.
// ---------------------------------------------------------------------------
__global__ __launch_bounds__(256) void k_init(int4* __restrict__ bwin4)
{
    int i = blockIdx.x * 256 + threadIdx.x;          // 32768 int4
    bwin4[i] = make_int4(-1, -1, -1, -1);
}

// ---------------------------------------------------------------------------
// Pass 1: block's 48 KB pc slab staged into LDS with float4 loads (coalesced,
// 4x fewer VMEM instrs), consumed from LDS. Slab aliases sb(16K)+stage(32K).
// Interior -> u64 entries pix(12b)<<52 | n(18b)<<32 | zbits, staged dense in
// LDS, dumped coalesced. Border -> sb[4096] pre-reduction -> bwin atomicMax.
// Dot products replicate numpy einsum k=4: separately-rounded products,
// pairwise association, fp contract OFF (bit-exact winner selection).
// ---------------------------------------------------------------------------
__global__ __launch_bounds__(BLK) void k_bin(
        const float* __restrict__ pc,   // (B,N,3)
        const float* __restrict__ tm,   // (B,3,4)
        unsigned long long* __restrict__ arena,
        unsigned int* __restrict__ tmeta,
        int* __restrict__ bwin)         // (B,4096) init -1
{
#pragma clang fp contract(off)
    const int b   = blockIdx.y;
    const int tid = threadIdx.x;
    const int gg  = b * NBLK + blockIdx.x;

    __shared__ __align__(16) char smem[49152];        // 48 KB, phase-aliased
    __shared__ unsigned int hist[NBAND];
    __shared__ unsigned int lofs[NBAND];

    float*              pcs   = (float*)smem;                     // ph 1-2
    float4*             pcs4  = (float4*)smem;
    int*                sb    = (int*)smem;                       // ph 3+
    unsigned long long* stage = (unsigned long long*)(smem + 16384);

    const int blk0     = blockIdx.x * BPB;
    const int npts_blk = min(BPB, NPTS - blk0);       // 4096 (3392 last)
    const float* pcb   = pc + (size_t)b * NPTS * 3;

    // ---- phase 1: cooperative float4 staging of this block's pc slab
    const int nf4 = (npts_blk * 3) >> 2;              // 3072 / 2544, exact
    const float4* src4 = (const float4*)pcb + ((size_t)blk0 * 3 >> 2);
    for (int i = tid; i < nf4; i += BLK) pcs4[i] = src4[i];
    if (tid < NBAND) hist[tid] = 0u;
    __syncthreads();

    // ---- phase 2: per-point transform + binning (reads from LDS)
    const float* M = tm + b * 12;
    const float m0 = M[0], m1 = M[1], m2  = M[2],  m3  = M[3];
    const float m4 = M[4], m5 = M[5], m6  = M[6],  m7  = M[7];
    const float m8 = M[8], m9 = M[9], m10 = M[10], m11 = M[11];

    unsigned long long ent[PPT];
    unsigned int rb[PPT];

    #pragma unroll
    for (int k = 0; k < PPT; ++k) {
        rb[k] = RB_INVALID;
        int j = k * BLK + tid;
        if (j < npts_blk) {
            float x = pcs[j * 3], y = pcs[j * 3 + 1], z = pcs[j * 3 + 2];
            float tx = (x * m0 + y * m1) + (z * m2  + m3);
            float ty = (x * m4 + y * m5) + (z * m6  + m7);
            float tz = (x * m8 + y * m9) + (z * m10 + m11);
            float nx = tx * 0.5f;
            float ny = ty * 0.5f;
            float nz = tz * 0.5f;
            float px = (nx + 1.0f) * 512.0f;
            float py = (1.0f - ny) * 512.0f;
            px = fminf(fmaxf(px, 0.0f), 1023.0f);
            py = fminf(fmaxf(py, 0.0f), 1023.0f);
            int xi = (int)floorf(px);
            int yi = (int)floorf(py);
            int n  = blk0 + j;

            bool border = (xi == 0) | (xi == 1023) | (yi == 0) | (yi == 1023);
            if (border) {
                int idx = (yi == 0)    ? xi
                        : (yi == 1023) ? 1024 + xi
                        : (xi == 0)    ? 2048 + yi
                                       : 3072 + yi;
                rb[k]  = RB_BORDER;
                ent[k] = ((unsigned long long)(unsigned)idx << 32) | (unsigned)n;
            } else {
                int bin = yi >> 2;                       // 4-row bands
                unsigned r = atomicAdd(&hist[bin], 1u);  // local rank
                rb[k] = ((unsigned)bin << 12) | r;       // r <= 4095
                unsigned pix = (unsigned)((yi & 3) * RES + xi);   // 12 bits
                ent[k] = ((unsigned long long)pix << 52)
                       | ((unsigned long long)(unsigned)n << 32)
                       | (unsigned long long)__float_as_uint(nz);
            }
        }
    }
    __syncthreads();   // pcs fully consumed; smem can be repurposed

    // ---- phase 3: sb init (aliases pcs!) + hist scan
    for (int k2 = tid; k2 < BORD; k2 += BLK) sb[k2] = -1;
    if (tid < 64) {
        unsigned carry = 0;
        #pragma unroll
        for (int c = 0; c < 4; ++c) {
            unsigned v = hist[c * 64 + tid];
            unsigned s = v;
            #pragma unroll
            for (int d = 1; d < 64; d <<= 1) {
                unsigned o = __shfl_up(s, d);
                if (tid >= d) s += o;
            }
            lofs[c * 64 + tid] = (s - v) + carry;
            carry += __shfl(s, 63);
        }
    }
    __syncthreads();

    // ---- phase 4: border -> sb atomics; interior -> stage; tmeta
    #pragma unroll
    for (int k = 0; k < PPT; ++k) {
        if (rb[k] == RB_BORDER) {
            atomicMax(&sb[(int)(ent[k] >> 32)], (int)(unsigned)ent[k]);
        } else if (rb[k] != RB_INVALID) {
            unsigned bin = rb[k] >> 12, r = rb[k] & 4095u;
            stage[lofs[bin] + r] = ent[k];
        }
    }
    if (tid < NBAND)
        tmeta[((size_t)(b * NBAND + tid)) * NBLK + blockIdx.x]
            = (lofs[tid] << 16) | hist[tid];
    __syncthreads();

    // ---- phase 5: coalesced dump + border flush
    const unsigned Ttot = lofs[NBAND - 1] + hist[NBAND - 1];
    for (unsigned k2 = tid; k2 < Ttot; k2 += BLK)
        arena[(size_t)gg * BPB + k2] = stage[k2];

    for (int k2 = tid; k2 < BORD; k2 += BLK) {
        int v = sb[k2];
        if (v >= 0) atomicMax(&bwin[b * BORD + k2], v);
    }
}

// ---------------------------------------------------------------------------
// Pass 2: one block per (batch, 4-row band), 512 threads, 32 KB u64 tile
// (4 blocks/CU). Hoisted tmeta load; wave-0 prefix scan of 49 segment counts;
// flat cooperative accumulate (idx->seg via 6-step LDS binary search);
// atomicMax key = n<<32|zbits; winner z = low word. Border pixels resolve
// from bwin. Non-temporal u64-packed output stores.
// ---------------------------------------------------------------------------
__global__ __launch_bounds__(512) void k_tile(
        const unsigned long long* __restrict__ arena,
        const unsigned int* __restrict__ tmeta,
        const int* __restrict__ bwin,
        const float* __restrict__ pc,
        const float* __restrict__ tm,
        float* __restrict__ out)
{
#pragma clang fp contract(off)
    const int bucket = blockIdx.x;            // 0 .. NB*NBAND-1
    const int b = bucket >> 8, band = bucket & 255;
    const int tid = threadIdx.x;

    __shared__ __align__(16) unsigned long long tile[BANDH * RES];  // 32768 B
    __shared__ unsigned int pref[NBLK + 1];
    __shared__ unsigned int sbase[NBLK];

    // hoisted meta load (overlaps with tile init below)
    unsigned mv = 0;
    if (tid < NBLK)
        mv = tmeta[((size_t)(b * NBAND + band)) * NBLK + tid];

    for (int k = tid; k < BANDH * RES; k += 512) tile[k] = 0ull;

    if (tid < 64) {
        unsigned cnt = (tid < NBLK) ? (mv & 0xFFFFu) : 0u;
        unsigned s = cnt;
        #pragma unroll
        for (int d = 1; d < 64; d <<= 1) {
            unsigned o = __shfl_up(s, d);
            if (tid >= d) s += o;
        }
        if (tid < NBLK) {
            pref[tid + 1] = s;
            sbase[tid] = (unsigned)((b * NBLK + tid) * BPB) + (mv >> 16);
        }
        if (tid == 0) pref[0] = 0u;
    }
    __syncthreads();

    const unsigned T = pref[NBLK];
    for (unsigned idx = tid; idx < T; idx += 512) {
        int lo = 0, hi = NBLK - 1;
        #pragma unroll
        for (int it = 0; it < 6; ++it) {                // ceil(log2(49)) = 6
            int mid = (lo + hi + 1) >> 1;
            if (pref[mid] <= idx) lo = mid; else hi = mid - 1;
        }
        unsigned long long e = arena[(size_t)sbase[lo] + (idx - pref[lo])];
        atomicMax(&tile[e >> 52], e & 0x000FFFFFFFFFFFFFull);
    }
    __syncthreads();

    const float* M2 = tm + b * 12 + 8;
    const float m8 = M2[0], m9 = M2[1], m10 = M2[2], m11 = M2[3];
    const int y0 = band * BANDH;
    const int* bw = bwin + b * BORD;

    for (int r = 0; r < BANDH; ++r) {
        int yi = y0 + r;
        ulonglong2 kk = ((const ulonglong2*)(tile + r * RES))[tid];
        unsigned zx = (unsigned)(kk.x & 0xFFFFFFFFull);
        unsigned zy = (unsigned)(kk.y & 0xFFFFFFFFull);

        #pragma unroll
        for (int h = 0; h < 2; ++h) {
            int xi = tid * 2 + h;
            bool isb = (yi == 0) | (yi == 1023) | (xi == 0) | (xi == 1023);
            if (isb) {
                int n = (yi == 0)    ? bw[xi]
                      : (yi == 1023) ? bw[1024 + xi]
                      : (xi == 0)    ? bw[2048 + yi]
                                     : bw[3072 + yi];
                float zv = 0.0f;
                if (n >= 0) {
                    const float* p = pc + ((size_t)b * NPTS + n) * 3;
                    float t = (p[0] * m8 + p[1] * m9) + (p[2] * m10 + m11);
                    zv = t * 0.5f;
                }
                if (h) zy = __float_as_uint(zv); else zx = __float_as_uint(zv);
            }
        }
        unsigned long long pv = ((unsigned long long)zy << 32) | zx;
        __builtin_nontemporal_store(pv,
            (unsigned long long*)(out + ((size_t)b * RES + yi) * RES) + tid);
    }
}

// ---------------------------------------------------------------------------
extern "C" void kernel_launch(void* const* d_in, const int* in_sizes, int n_in,
                              void* d_out, int out_size, void* d_ws, size_t ws_size,
                              hipStream_t stream)
{
    const float* pc = (const float*)d_in[0];   // (32,200000,3) f32
    const float* tm = (const float*)d_in[1];   // (32,3,4) f32
    float* out = (float*)d_out;                // (32,1024,1024) f32

    char* ws = (char*)d_ws;
    unsigned long long* arena = (unsigned long long*)(ws + OFF_AR);
    unsigned int* tmeta = (unsigned int*)(ws + OFF_TM);
    int*          bwin  = (int*)         (ws + OFF_BW);

    k_init<<<(NB * BORD / 4) / 256, 256, 0, stream>>>((int4*)bwin);

    dim3 g1(NBLK, NB);
    k_bin<<<g1, BLK, 0, stream>>>(pc, tm, arena, tmeta, bwin);

    k_tile<<<NB * NBAND, 512, 0, stream>>>(arena, tmeta, bwin, pc, tm, out);
}